// Round 3
// baseline (2340.742 us; speedup 1.0000x reference)
//
#include <hip/hip_runtime.h>
#include <hip/hip_bf16.h>
#include <math.h>

typedef __bf16 bf16;
typedef __bf16 bf16x8 __attribute__((ext_vector_type(8)));
typedef __bf16 bf16x4 __attribute__((ext_vector_type(4)));
typedef float f32x4 __attribute__((ext_vector_type(4)));
typedef unsigned int u32;
typedef u32 u32x4 __attribute__((ext_vector_type(4)));

#define NINP 400
#define HS   1000
#define HP   1024
#define B_   8
#define T_   256
#define NT   2048   /* B_*T_ */
#define K2   2048   /* 2*HP  */
#define K1   1024   /* 2*512 */
#define M_   4096   /* 4 gates * HP */

#define HT_OFF   819200
#define CT_OFF   827200
#define AUX_OFF  835200

typedef __attribute__((address_space(1))) const void gvoid;
typedef __attribute__((address_space(3))) void lvoid;

__device__ __forceinline__ void async_copy16(void* lds, const void* g) {
  __builtin_amdgcn_global_load_lds((gvoid*)g, (lvoid*)lds, 16, 0, 0);
}

__device__ __forceinline__ float sigm(float x) { return 1.0f / (1.0f + expf(-x)); }

// ---------------- repack kernels (fp32 inputs -> packed-m bf16) ----------------
// M-packing (unchanged): pm = (h>>5)*128 + ((h>>4)&1)*64 + g*16 + (h&15)
// A 256-pm block bm covers h in [bm*64, bm*64+64); wave mh's 4 m-tiles = gates
// 0..3 of h-subgroup (bm*64 + mh*16 .. +16). C-layout (16x16): col=lane&15,
// row=quad*4+reg -> all 4 gates of a given h land in the same lane/reg across
// acc[0..3] -> lane-local gating.

__global__ void repack_w1(const float* __restrict__ w1, bf16* __restrict__ W1q) {
  int idx = blockIdx.x * 256 + threadIdx.x;           // 4096*1024
  if (idx >= M_ * K1) return;
  int pm = idx >> 10, k = idx & 1023;
  int g = (pm >> 4) & 3;
  int h = (pm >> 7) * 32 + ((pm >> 6) & 1) * 16 + (pm & 15);
  float v = 0.0f;
  if (h < HS) {
    int c = g * HS + h;
    if (k < 512) { if (k < NINP) v = w1[(size_t)c * (NINP * 2) + k * 2 + 0]; }
    else { int j = k - 512; if (j < NINP) v = w1[(size_t)c * (NINP * 2) + j * 2 + 1]; }
  }
  W1q[idx] = (bf16)v;
}

__global__ void repack_w2(const float* __restrict__ w2, bf16* __restrict__ W2q) {
  int idx = blockIdx.x * 256 + threadIdx.x;           // 4096*2048
  if (idx >= M_ * K2) return;
  int pm = idx >> 11, k = idx & 2047;
  int g = (pm >> 4) & 3;
  int h = (pm >> 7) * 32 + ((pm >> 6) & 1) * 16 + (pm & 15);
  float v = 0.0f;
  if (h < HS) {
    int c = g * HS + h;
    if (k < HP) { if (k < HS) v = w2[(size_t)c * (HS * 2) + k * 2 + 0]; }
    else { int j = k - HP; if (j < HS) v = w2[(size_t)c * (HS * 2) + j * 2 + 1]; }
  }
  W2q[idx] = (bf16)v;
}

__global__ void build_xt(const float* __restrict__ X, bf16* __restrict__ XT) {
  int idx = blockIdx.x * 256 + threadIdx.x;           // 2048*1024
  if (idx >= NT * K1) return;
  int n = idx >> 10, k = idx & 1023;
  int b = n >> 8, t = n & (T_ - 1);
  float v = 0.0f;
  if (k < 512) { if (k < NINP && t > 0) v = X[((size_t)b * NINP + k) * T_ + t - 1]; }
  else { int j = k - 512; if (j < NINP) v = X[((size_t)b * NINP + j) * T_ + t]; }
  XT[idx] = (bf16)v;
}

__global__ void build_hc(const float* __restrict__ hid, const float* __restrict__ cell,
                         bf16* __restrict__ hidp, float* __restrict__ cellp) {
  int idx = blockIdx.x * 256 + threadIdx.x;           // 8*1024
  if (idx >= B_ * HP) return;
  int b = idx >> 10, k = idx & (HP - 1);
  hidp[idx]  = (k < HS) ? (bf16)hid[b * HS + k] : (bf16)0.0f;
  cellp[idx] = (k < HS) ? cell[b * HS + k] : 0.0f;
}

// ---------------- fused GEMM (+gating), 16x16x32 MFMA ----------------
// BM=256 x BN=128, BK=64, 8 waves (512 thr), wave = 64x64 (4mt x 4nt of 16x16).
// Counted-vmcnt software pipeline (T3+T4), 3 LDS buffers (144 KB), tile j ->
// buf j%3, prefetch depth ~1.5 tiles:
//   prologue: stage(t0), stage(t1)
//   iter t:   s_waitcnt vmcnt(6)   <- tile t resident; tile t+1's 6 loads ride
//             s_barrier            <- all waves see tile t / done reading t-1
//             stage tile t+2       <- overwrites buf (t-1)%3 (safe: see above);
//                                     issued BEFORE compute so its HBM/L2
//                                     latency hides under ~2 compute phases
//             compute buf t%3      <- 64 MFMA, setprio(1) around clusters
// ONE barrier + ONE counted wait per K-tile; vmcnt never drains to 0 in the
// main loop (the m218 lever).  Fragment reads keep the proven source-rotation
// conflict-free idiom (swo / chunk=((kc>>3)+quad+row)&7).  Gated: CbIn (conv1,
// step-invariant) prefetched into registers before the K-loop (oldest in the
// vmcnt FIFO -> drained once at iter 0).

template <bool GATED>
__global__ __launch_bounds__(512, 2) void gemm_step(
    const bf16* __restrict__ A,      // W2q [4096][2048] or W1q [4096][1024] packed-m
    const bf16* __restrict__ Bsrc,   // gated: Hprev [NT][HP]; plain: XT [NT][K1]
    const bf16* __restrict__ hidp,   // [B_][HP]
    const bf16* __restrict__ CbIn,   // gated: CbP [NT][4096] packed-m
    bf16* __restrict__ CbOut,        // plain: write CbP
    const float* __restrict__ b2,
    const bf16* __restrict__ ctprev, // [HP][NT]
    const float* __restrict__ cellp, // [B_][HP]
    bf16* __restrict__ ctnew,        // [HP][NT]
    bf16* __restrict__ Hnew,         // [NT][HP]
    int K) {
  __shared__ bf16 As[3][256][64];    // 96 KB
  __shared__ bf16 Bs[3][128][64];    // 48 KB

  const int tid = threadIdx.x;
  const int lane = tid & 63;
  const int w = tid >> 6;            // 0..7
  const int mh = w >> 1;             // 0..3 (64-row A strip)
  const int nh = w & 1;              // 0..1 (64-col B strip)
  const int dr = lane >> 3, c8 = lane & 7;
  const int swo = ((c8 - dr) & 7) * 8;     // staging source rotation
  const int quad = lane >> 4, col = lane & 15;

  // XCD-aware bijective swizzle over 256 blocks: xcd L&7 owns bm {2x,2x+1}
  // (2 MB W2q slice per XCD L2) x 16 n-blocks.
  const int L = blockIdx.y * 16 + blockIdx.x;
  const int bm = (L & 7) * 2 + (L >> 7);           // 0..15 (256-pm blocks)
  const int n0 = ((L >> 3) & 15) * 128;

  // ---- gated: prefetch step-invariant conv1 contribution into registers ----
  bf16x4 cb0[4], cb1[4], cb2[4], cb3[4];
  if (GATED) {
#pragma unroll
    for (int nt = 0; nt < 4; ++nt) {
      const int n = n0 + nh * 64 + nt * 16 + col;
      const size_t cb = (size_t)n * 4096 + (size_t)(bm * 256 + mh * 64) + quad * 4;
      cb0[nt] = *(const bf16x4*)&CbIn[cb + 0];
      cb1[nt] = *(const bf16x4*)&CbIn[cb + 16];
      cb2[nt] = *(const bf16x4*)&CbIn[cb + 32];
      cb3[nt] = *(const bf16x4*)&CbIn[cb + 48];
    }
  }

  f32x4 acc[4][4];
#pragma unroll
  for (int i = 0; i < 4; ++i)
#pragma unroll
    for (int j = 0; j < 4; ++j) acc[i][j] = (f32x4){0.f, 0.f, 0.f, 0.f};

  // ---- staging: 6 x 16B gload_lds per thread per K-tile (A:4, B:2) ----
  auto stage = [&](int buf, int it2) {
    const int k0 = it2 << 6;
#pragma unroll
    for (int i = 0; i < 4; ++i) {
      const int r = i * 64 + w * 8 + dr;
      async_copy16(&As[buf][i * 64 + w * 8][0],
                   A + (size_t)(bm * 256 + r) * K + k0 + swo);
    }
#pragma unroll
    for (int j = 0; j < 2; ++j) {
      const int r = j * 64 + w * 8 + dr;
      const int n = n0 + r;
      const bf16* bp;
      if (GATED) {
        const int kk = (k0 & (HP - 1)) + swo;
        if (k0 < HP) {
          const int t = n & (T_ - 1);
          bp = (t == 0) ? (hidp + (size_t)(n >> 8) * HP + kk)
                        : (Bsrc + (size_t)(n - 1) * HP + kk);
        } else {
          bp = Bsrc + (size_t)n * HP + kk;
        }
      } else {
        bp = Bsrc + (size_t)n * K + k0 + swo;
      }
      async_copy16(&Bs[buf][j * 64 + w * 8][0], bp);
    }
  };

  const int NIT = K >> 6;            // 16 or 32
  stage(0, 0);
  stage(1, 1);
  int cur = 0;
  for (int it = 0; it < NIT; ++it) {
    if (it + 1 < NIT) asm volatile("s_waitcnt vmcnt(6)" ::: "memory");
    else              asm volatile("s_waitcnt vmcnt(0)" ::: "memory");
    __builtin_amdgcn_s_barrier();
    if (it + 2 < NIT) {
      int nx = cur + 2; if (nx >= 3) nx -= 3;
      stage(nx, it + 2);             // overwrites buf (it-1)%3 — reads of it
                                     // finished before this iter's barrier
    }
#pragma unroll
    for (int kc = 0; kc < 64; kc += 32) {
      bf16x8 av[4], bv[4];
#pragma unroll
      for (int mt = 0; mt < 4; ++mt) {
        const int rA = mh * 64 + mt * 16 + col;
        av[mt] = *(const bf16x8*)&As[cur][rA][(((kc >> 3) + quad + rA) & 7) * 8];
      }
#pragma unroll
      for (int nt = 0; nt < 4; ++nt) {
        const int rB = nh * 64 + nt * 16 + col;
        bv[nt] = *(const bf16x8*)&Bs[cur][rB][(((kc >> 3) + quad + rB) & 7) * 8];
      }
      __builtin_amdgcn_s_setprio(1);
#pragma unroll
      for (int mt = 0; mt < 4; ++mt)
#pragma unroll
        for (int nt = 0; nt < 4; ++nt)
          acc[mt][nt] = __builtin_amdgcn_mfma_f32_16x16x32_bf16(av[mt], bv[nt], acc[mt][nt], 0, 0, 0);
      __builtin_amdgcn_s_setprio(0);
    }
    cur = (cur == 2) ? 0 : cur + 1;
  }
  __syncthreads();                   // all waves done computing; drain for epilogue

  if (!GATED) {
    // epilogue: pack C block [128 n][256 pm] via LDS overlay on As (64 KB)
    bf16 (*Csh)[256] = (bf16(*)[256])&As[0][0][0];
#pragma unroll
    for (int mt = 0; mt < 4; ++mt) {        // mt = gate
#pragma unroll
      for (int nt = 0; nt < 4; ++nt) {
        const int nloc = nh * 64 + nt * 16 + col;
        bf16x4 v;
#pragma unroll
        for (int j = 0; j < 4; ++j) {
          const int h = bm * 64 + mh * 16 + quad * 4 + j;
          const float bias = (h < HS) ? b2[mt * HS + h] : 0.0f;
          v[j] = (bf16)(acc[mt][nt][j] + bias);
        }
        *(bf16x4*)&Csh[nloc][mh * 64 + mt * 16 + quad * 4] = v;
      }
    }
    __syncthreads();
#pragma unroll
    for (int i2 = 0; i2 < 8; ++i2) {
      const int idx = i2 * 512 + tid;       // 128 rows x 32 chunks of 16B
      const int rrow = idx >> 5, off = idx & 31;
      *(u32x4*)&CbOut[(size_t)(n0 + rrow) * 4096 + bm * 256 + off * 8] =
          *(const u32x4*)&Csh[rrow][off * 8];
    }
  } else {
    bf16 (*Hsh)[64] = (bf16(*)[64])&As[0][0][0];   // [128 n][64 h] = 16 KB
#pragma unroll
    for (int nt = 0; nt < 4; ++nt) {
      const int nloc = nh * 64 + nt * 16 + col;
      const int n = n0 + nloc;
      const int b = n >> 8;
      const int t = n & (T_ - 1);
      bf16x4 hv;
#pragma unroll
      for (int j = 0; j < 4; ++j) {
        const int h = bm * 64 + mh * 16 + quad * 4 + j;
        const float ci = acc[0][nt][j] + (float)cb0[nt][j];
        const float co = acc[1][nt][j] + (float)cb1[nt][j];
        const float cg = acc[2][nt][j] + (float)cb2[nt][j];
        const float cf = acc[3][nt][j] + (float)cb3[nt][j];
        const float ctold = (t == 0) ? cellp[b * HP + h]
                                     : (float)ctprev[(size_t)h * NT + (n - 1)];
        const float cn = sigm(cf) * ctold + sigm(ci) * tanhf(cg);
        ctnew[(size_t)h * NT + n] = (bf16)cn;
        hv[j] = (bf16)(sigm(co) * tanhf(cn));
      }
      *(bf16x4*)&Hsh[nloc][mh * 16 + quad * 4] = hv;
    }
    __syncthreads();
#pragma unroll
    for (int i2 = 0; i2 < 2; ++i2) {
      const int idx = i2 * 512 + tid;       // 128 rows x 8 chunks of 16B
      const int rrow = idx >> 3, off = idx & 7;
      *(u32x4*)&Hnew[(size_t)(n0 + rrow) * HP + bm * 64 + off * 8] =
          *(const u32x4*)&Hsh[rrow][off * 8];
    }
  }
}

// ---------------- output kernels (fp32 out) ----------------

__global__ void aux_kernel(const bf16* __restrict__ H, float* __restrict__ out, int s) {
  int idx = blockIdx.x * 256 + threadIdx.x;  // 8*256*100
  if (idx >= NT * 100) return;
  int n = idx / 100;
  int o = (idx % 100) * 4;
  int b = n >> 8, t = n & (T_ - 1);
  bf16x4 v = *(const bf16x4*)&H[(size_t)n * HP + 600 + o];
  f32x4 f = {(float)v[0], (float)v[1], (float)v[2], (float)v[3]};
  *(f32x4*)&out[AUX_OFF + ((size_t)((b * 2 + s) * T_ + t)) * 400 + o] = f;
}

__global__ void final_kernel(const bf16* __restrict__ H, const bf16* __restrict__ ct,
                             float* __restrict__ out) {
  int idx = blockIdx.x * 256 + threadIdx.x;
  if (idx < NT * 100) {
    int n = idx / 100;
    int o = (idx % 100) * 4;
    int b = n >> 8, t = n & (T_ - 1);
    bf16x4 v = *(const bf16x4*)&H[(size_t)n * HP + 600 + o];
    f32x4 f = {(float)v[0], (float)v[1], (float)v[2], (float)v[3]};
    *(f32x4*)&out[(size_t)n * 400 + o] = f;  // out_main [b][t][400]
    *(f32x4*)&out[AUX_OFF + ((size_t)((b * 2 + 1) * T_ + t)) * 400 + o] = f;
  } else {
    int j = idx - NT * 100;
    if (j < 8000) {
      int b = j / 1000, h = j % 1000;
      out[HT_OFF + j] = (float)H[(size_t)(b * T_ + 255) * HP + h];
    } else if (j < 16000) {
      int jj = j - 8000;
      int b = jj / 1000, h = jj % 1000;
      out[CT_OFF + jj] = (float)ct[(size_t)h * NT + b * T_ + 255];
    }
  }
}

// ---------------- launch ----------------

extern "C" void kernel_launch(void* const* d_in, const int* in_sizes, int n_in,
                              void* d_out, int out_size, void* d_ws, size_t ws_size,
                              hipStream_t stream) {
  const float* X    = (const float*)d_in[0];
  const float* hid  = (const float*)d_in[1];
  const float* cell = (const float*)d_in[2];
  const float* w1   = (const float*)d_in[3];
  const float* w2   = (const float*)d_in[4];
  const float* b2   = (const float*)d_in[5];
  float* out = (float*)d_out;

  char* ws = (char*)d_ws;
  size_t off = 0;
  auto alloc = [&](size_t bytes) {
    void* p = ws + off;
    off += (bytes + 255) & ~(size_t)255;
    return p;
  };
  bf16* W2q    = (bf16*)alloc((size_t)M_ * K2 * 2);     // 16 MB
  bf16* CbP    = (bf16*)alloc((size_t)NT * M_ * 2);     // 16 MB
  bf16* Hb0    = (bf16*)alloc((size_t)NT * HP * 2);     // 4 MB
  bf16* ctb0   = (bf16*)alloc((size_t)HP * NT * 2);     // 4 MB
  bf16* hidp   = (bf16*)alloc((size_t)B_ * HP * 2);
  float* cellp = (float*)alloc((size_t)B_ * HP * 4);
  // Union region: {W1q, XT} live only until the first GEMM; then {ctb1, Hb1}.
  char* R = (char*)alloc((size_t)12 * 1024 * 1024);     // 12 MB
  bf16* W1q  = (bf16*)R;                                // 8 MB
  bf16* XT   = (bf16*)(R + (size_t)8 * 1024 * 1024);    // 4 MB
  bf16* ctb1 = (bf16*)R;                                // 4 MB
  bf16* Hb1  = (bf16*)(R + (size_t)4 * 1024 * 1024);    // 4 MB

  bf16* Hb[2]  = {Hb0, Hb1};
  bf16* ctb[2] = {ctb0, ctb1};

  hipMemsetAsync(Hb[0], 0, (size_t)NT * HP * 2, stream);
  hipMemsetAsync(ctb[0], 0, (size_t)HP * NT * 2, stream);

  repack_w1<<<(M_ * K1) / 256, 256, 0, stream>>>(w1, W1q);
  repack_w2<<<(M_ * K2) / 256, 256, 0, stream>>>(w2, W2q);
  build_xt<<<(NT * K1) / 256, 256, 0, stream>>>(X, XT);
  build_hc<<<(B_ * HP) / 256, 256, 0, stream>>>(hid, cell, hidp, cellp);

  dim3 grid(16, 16);  // 256 blocks, 1/CU (144 KB LDS)
  gemm_step<false><<<grid, 512, 0, stream>>>(W1q, XT, nullptr, nullptr, CbP, b2,
                                             nullptr, nullptr, nullptr, nullptr, K1);
  for (int i = 0; i < 40; ++i) {
    int p = i & 1;
    gemm_step<true><<<grid, 512, 0, stream>>>(W2q, Hb[p], hidp, CbP, nullptr, nullptr,
                                              ctb[p], cellp, ctb[p ^ 1], Hb[p ^ 1], K2);
    if (i == 19) aux_kernel<<<800, 256, 0, stream>>>(Hb[p ^ 1], out, 0);
  }
  final_kernel<<<(NT * 100 + 16000 + 255) / 256, 256, 0, stream>>>(Hb[0], ctb[0], out);
}

// Round 4
// 1970.262 us; speedup vs baseline: 1.1880x; 1.1880x over previous
//
#include <hip/hip_runtime.h>
#include <hip/hip_bf16.h>
#include <math.h>

typedef __bf16 bf16;
typedef __bf16 bf16x8 __attribute__((ext_vector_type(8)));
typedef __bf16 bf16x4 __attribute__((ext_vector_type(4)));
typedef float f32x4 __attribute__((ext_vector_type(4)));
typedef unsigned int u32;
typedef u32 u32x4 __attribute__((ext_vector_type(4)));

#define NINP 400
#define HS   1000
#define HP   1024
#define B_   8
#define T_   256
#define NT   2048   /* B_*T_ */
#define K2   2048   /* 2*HP  */
#define K1   1024   /* 2*512 */
#define M_   4096   /* 4 gates * HP */

#define HT_OFF   819200
#define CT_OFF   827200
#define AUX_OFF  835200

typedef __attribute__((address_space(1))) const void gvoid;
typedef __attribute__((address_space(3))) void lvoid;

__device__ __forceinline__ void async_copy16(void* lds, const void* g) {
  __builtin_amdgcn_global_load_lds((gvoid*)g, (lvoid*)lds, 16, 0, 0);
}

__device__ __forceinline__ float sigm(float x) { return 1.0f / (1.0f + expf(-x)); }

// ---------------- repack kernels (fp32 inputs -> packed-m bf16) ----------------
// M-packing (unchanged): pm = (h>>5)*128 + ((h>>4)&1)*64 + g*16 + (h&15)
// A 256-pm block bm covers h in [bm*64, bm*64+64); wave mh's 4 m-tiles = gates
// 0..3 of h-subgroup (bm*64 + mh*16 .. +16). C-layout (16x16): col=lane&15,
// row=quad*4+reg -> all 4 gates of a given h land in the same lane/reg across
// acc[0..3] -> lane-local gating.

__global__ void repack_w1(const float* __restrict__ w1, bf16* __restrict__ W1q) {
  int idx = blockIdx.x * 256 + threadIdx.x;           // 4096*1024
  if (idx >= M_ * K1) return;
  int pm = idx >> 10, k = idx & 1023;
  int g = (pm >> 4) & 3;
  int h = (pm >> 7) * 32 + ((pm >> 6) & 1) * 16 + (pm & 15);
  float v = 0.0f;
  if (h < HS) {
    int c = g * HS + h;
    if (k < 512) { if (k < NINP) v = w1[(size_t)c * (NINP * 2) + k * 2 + 0]; }
    else { int j = k - 512; if (j < NINP) v = w1[(size_t)c * (NINP * 2) + j * 2 + 1]; }
  }
  W1q[idx] = (bf16)v;
}

__global__ void repack_w2(const float* __restrict__ w2, bf16* __restrict__ W2q) {
  int idx = blockIdx.x * 256 + threadIdx.x;           // 4096*2048
  if (idx >= M_ * K2) return;
  int pm = idx >> 11, k = idx & 2047;
  int g = (pm >> 4) & 3;
  int h = (pm >> 7) * 32 + ((pm >> 6) & 1) * 16 + (pm & 15);
  float v = 0.0f;
  if (h < HS) {
    int c = g * HS + h;
    if (k < HP) { if (k < HS) v = w2[(size_t)c * (HS * 2) + k * 2 + 0]; }
    else { int j = k - HP; if (j < HS) v = w2[(size_t)c * (HS * 2) + j * 2 + 1]; }
  }
  W2q[idx] = (bf16)v;
}

__global__ void build_xt(const float* __restrict__ X, bf16* __restrict__ XT) {
  int idx = blockIdx.x * 256 + threadIdx.x;           // 2048*1024
  if (idx >= NT * K1) return;
  int n = idx >> 10, k = idx & 1023;
  int b = n >> 8, t = n & (T_ - 1);
  float v = 0.0f;
  if (k < 512) { if (k < NINP && t > 0) v = X[((size_t)b * NINP + k) * T_ + t - 1]; }
  else { int j = k - 512; if (j < NINP) v = X[((size_t)b * NINP + j) * T_ + t]; }
  XT[idx] = (bf16)v;
}

__global__ void build_hc(const float* __restrict__ hid, const float* __restrict__ cell,
                         bf16* __restrict__ hidp, float* __restrict__ cellp) {
  int idx = blockIdx.x * 256 + threadIdx.x;           // 8*1024
  if (idx >= B_ * HP) return;
  int b = idx >> 10, k = idx & (HP - 1);
  hidp[idx]  = (k < HS) ? (bf16)hid[b * HS + k] : (bf16)0.0f;
  cellp[idx] = (k < HS) ? cell[b * HS + k] : 0.0f;
}

// ---------------- fused GEMM (+gating), 16x16x32 MFMA ----------------
// BM=256 x BN=128, BK=64, 8 waves (512 thr), wave = 64x64 (4mt x 4nt of 16x16).
// m201-style phase schedule: per K-tile, TWO phases (kc=0,32), each
//   { 8 ds_read_b128 (this phase's frags)  ||  3 global_load_lds (tile t+2)
//     -> s_barrier -> lgkmcnt(0)+sched_barrier -> setprio(1) 16xMFMA setprio(0)
//     -> s_barrier }
// The entry barrier groups all 8 waves' ds_reads into one full-parallel LDS
// burst abutting the previous phase's MFMA burst (kills the alternation dead
// time measured in r1/r3: MfmaUtil 22%, no pipe >45%).  3 LDS buffers, tile
// j -> buf j%3; per-tile s_waitcnt vmcnt(6) before the LAST phase's entry
// barrier (in-order retirement: newest 6 outstanding = tile t+2's loads; so
// <=6 outstanding  =>  tile t+1 resident; barrier publishes to all waves).
// vmcnt never drains to 0 in steady state (T4); vmcnt(0) only when nothing
// was staged this iteration (tail).  Fragment reads keep the proven
// source-rotation conflict-free idiom (swo / chunk=((kc>>3)+quad+row)&7).
// Gated: CbIn (conv1, step-invariant) loads are issued FIRST (oldest in the
// vmcnt FIFO -> retired before any counted wait matters).

template <bool GATED>
__global__ __launch_bounds__(512, 2) void gemm_step(
    const bf16* __restrict__ A,      // W2q [4096][2048] or W1q [4096][1024] packed-m
    const bf16* __restrict__ Bsrc,   // gated: Hprev [NT][HP]; plain: XT [NT][K1]
    const bf16* __restrict__ hidp,   // [B_][HP]
    const bf16* __restrict__ CbIn,   // gated: CbP [NT][4096] packed-m
    bf16* __restrict__ CbOut,        // plain: write CbP
    const float* __restrict__ b2,
    const bf16* __restrict__ ctprev, // [HP][NT]
    const float* __restrict__ cellp, // [B_][HP]
    bf16* __restrict__ ctnew,        // [HP][NT]
    bf16* __restrict__ Hnew,         // [NT][HP]
    int K) {
  __shared__ bf16 As[3][256][64];    // 96 KB
  __shared__ bf16 Bs[3][128][64];    // 48 KB

  const int tid = threadIdx.x;
  const int lane = tid & 63;
  const int w = tid >> 6;            // 0..7
  const int mh = w >> 1;             // 0..3 (64-row A strip)
  const int nh = w & 1;              // 0..1 (64-col B strip)
  const int dr = lane >> 3, c8 = lane & 7;
  const int swo = ((c8 - dr) & 7) * 8;     // staging source rotation
  const int quad = lane >> 4, col = lane & 15;

  // XCD-aware bijective swizzle over 256 blocks: xcd L&7 owns bm {2x,2x+1}
  // (2 MB W2q slice per XCD L2) x 16 n-blocks.
  const int L = blockIdx.y * 16 + blockIdx.x;
  const int bm = (L & 7) * 2 + (L >> 7);           // 0..15 (256-pm blocks)
  const int n0 = ((L >> 3) & 15) * 128;

  // ---- gated: prefetch step-invariant conv1 contribution into registers ----
  bf16x4 cb0[4], cb1[4], cb2[4], cb3[4];
  if (GATED) {
#pragma unroll
    for (int nt = 0; nt < 4; ++nt) {
      const int n = n0 + nh * 64 + nt * 16 + col;
      const size_t cb = (size_t)n * 4096 + (size_t)(bm * 256 + mh * 64) + quad * 4;
      cb0[nt] = *(const bf16x4*)&CbIn[cb + 0];
      cb1[nt] = *(const bf16x4*)&CbIn[cb + 16];
      cb2[nt] = *(const bf16x4*)&CbIn[cb + 32];
      cb3[nt] = *(const bf16x4*)&CbIn[cb + 48];
    }
  }

  f32x4 acc[4][4];
#pragma unroll
  for (int i = 0; i < 4; ++i)
#pragma unroll
    for (int j = 0; j < 4; ++j) acc[i][j] = (f32x4){0.f, 0.f, 0.f, 0.f};

  // ---- staging halves: 3 glds each (A:4 + B:2 = 6 per tile total) ----
  auto stage_h0 = [&](int buf, int it2) {          // A rows 0..2
    const int k0 = it2 << 6;
#pragma unroll
    for (int i = 0; i < 3; ++i) {
      const int r = i * 64 + w * 8 + dr;
      async_copy16(&As[buf][i * 64 + w * 8][0],
                   A + (size_t)(bm * 256 + r) * K + k0 + swo);
    }
  };
  auto stage_h1 = [&](int buf, int it2) {          // A row 3 + B rows 0,1
    const int k0 = it2 << 6;
    {
      const int r = 3 * 64 + w * 8 + dr;
      async_copy16(&As[buf][3 * 64 + w * 8][0],
                   A + (size_t)(bm * 256 + r) * K + k0 + swo);
    }
#pragma unroll
    for (int j = 0; j < 2; ++j) {
      const int r = j * 64 + w * 8 + dr;
      const int n = n0 + r;
      const bf16* bp;
      if (GATED) {
        const int kk = (k0 & (HP - 1)) + swo;
        if (k0 < HP) {
          const int t = n & (T_ - 1);
          bp = (t == 0) ? (hidp + (size_t)(n >> 8) * HP + kk)
                        : (Bsrc + (size_t)(n - 1) * HP + kk);
        } else {
          bp = Bsrc + (size_t)n * HP + kk;
        }
      } else {
        bp = Bsrc + (size_t)n * K + k0 + swo;
      }
      async_copy16(&Bs[buf][j * 64 + w * 8][0], bp);
    }
  };

  const int NIT = K >> 6;            // 16 or 32
  stage_h0(0, 0); stage_h1(0, 0);
  stage_h0(1, 1); stage_h1(1, 1);
  asm volatile("s_waitcnt vmcnt(6)" ::: "memory");  // tile 0 resident (in-order)
  __builtin_amdgcn_s_barrier();

  int cur = 0;
  for (int it = 0; it < NIT; ++it) {
    const bool pre = (it + 2 < NIT);
    int nx = cur + 2; if (nx >= 3) nx -= 3;        // buf of tile t+2 (= old t-1)

    // ================= phase 0 (kc = 0) =================
    {
      bf16x8 av[4], bv[4];
#pragma unroll
      for (int mt = 0; mt < 4; ++mt) {
        const int rA = mh * 64 + mt * 16 + col;
        av[mt] = *(const bf16x8*)&As[cur][rA][((quad + rA) & 7) * 8];
      }
#pragma unroll
      for (int nt = 0; nt < 4; ++nt) {
        const int rB = nh * 64 + nt * 16 + col;
        bv[nt] = *(const bf16x8*)&Bs[cur][rB][((quad + rB) & 7) * 8];
      }
      if (pre) stage_h0(nx, it + 2);
      __builtin_amdgcn_s_barrier();
      asm volatile("s_waitcnt lgkmcnt(0)" ::: "memory");
      __builtin_amdgcn_sched_barrier(0);
      __builtin_amdgcn_s_setprio(1);
#pragma unroll
      for (int mt = 0; mt < 4; ++mt)
#pragma unroll
        for (int nt = 0; nt < 4; ++nt)
          acc[mt][nt] = __builtin_amdgcn_mfma_f32_16x16x32_bf16(av[mt], bv[nt], acc[mt][nt], 0, 0, 0);
      __builtin_amdgcn_s_setprio(0);
      __builtin_amdgcn_s_barrier();
    }

    // ================= phase 1 (kc = 32) =================
    {
      bf16x8 av[4], bv[4];
#pragma unroll
      for (int mt = 0; mt < 4; ++mt) {
        const int rA = mh * 64 + mt * 16 + col;
        av[mt] = *(const bf16x8*)&As[cur][rA][((4 + quad + rA) & 7) * 8];
      }
#pragma unroll
      for (int nt = 0; nt < 4; ++nt) {
        const int rB = nh * 64 + nt * 16 + col;
        bv[nt] = *(const bf16x8*)&Bs[cur][rB][((4 + quad + rB) & 7) * 8];
      }
      if (pre) stage_h1(nx, it + 2);
      // tile t+1 must be resident for next iter: newest <=6 outstanding are
      // tile t+2's (staged this iter); if nothing staged, drain.
      if (pre) asm volatile("s_waitcnt vmcnt(6)" ::: "memory");
      else     asm volatile("s_waitcnt vmcnt(0)" ::: "memory");
      __builtin_amdgcn_s_barrier();
      asm volatile("s_waitcnt lgkmcnt(0)" ::: "memory");
      __builtin_amdgcn_sched_barrier(0);
      __builtin_amdgcn_s_setprio(1);
#pragma unroll
      for (int mt = 0; mt < 4; ++mt)
#pragma unroll
        for (int nt = 0; nt < 4; ++nt)
          acc[mt][nt] = __builtin_amdgcn_mfma_f32_16x16x32_bf16(av[mt], bv[nt], acc[mt][nt], 0, 0, 0);
      __builtin_amdgcn_s_setprio(0);
      __builtin_amdgcn_s_barrier();
    }

    cur = (cur == 2) ? 0 : cur + 1;
  }
  __syncthreads();                   // drain everything for epilogue overlay

  if (!GATED) {
    // epilogue: pack C block [128 n][256 pm] via LDS overlay on As (64 KB)
    bf16 (*Csh)[256] = (bf16(*)[256])&As[0][0][0];
#pragma unroll
    for (int mt = 0; mt < 4; ++mt) {        // mt = gate
#pragma unroll
      for (int nt = 0; nt < 4; ++nt) {
        const int nloc = nh * 64 + nt * 16 + col;
        bf16x4 v;
#pragma unroll
        for (int j = 0; j < 4; ++j) {
          const int h = bm * 64 + mh * 16 + quad * 4 + j;
          const float bias = (h < HS) ? b2[mt * HS + h] : 0.0f;
          v[j] = (bf16)(acc[mt][nt][j] + bias);
        }
        *(bf16x4*)&Csh[nloc][mh * 64 + mt * 16 + quad * 4] = v;
      }
    }
    __syncthreads();
#pragma unroll
    for (int i2 = 0; i2 < 8; ++i2) {
      const int idx = i2 * 512 + tid;       // 128 rows x 32 chunks of 16B
      const int rrow = idx >> 5, off = idx & 31;
      *(u32x4*)&CbOut[(size_t)(n0 + rrow) * 4096 + bm * 256 + off * 8] =
          *(const u32x4*)&Csh[rrow][off * 8];
    }
  } else {
    bf16 (*Hsh)[64] = (bf16(*)[64])&As[0][0][0];   // [128 n][64 h] = 16 KB
#pragma unroll
    for (int nt = 0; nt < 4; ++nt) {
      const int nloc = nh * 64 + nt * 16 + col;
      const int n = n0 + nloc;
      const int b = n >> 8;
      const int t = n & (T_ - 1);
      bf16x4 hv;
#pragma unroll
      for (int j = 0; j < 4; ++j) {
        const int h = bm * 64 + mh * 16 + quad * 4 + j;
        const float ci = acc[0][nt][j] + (float)cb0[nt][j];
        const float co = acc[1][nt][j] + (float)cb1[nt][j];
        const float cg = acc[2][nt][j] + (float)cb2[nt][j];
        const float cf = acc[3][nt][j] + (float)cb3[nt][j];
        const float ctold = (t == 0) ? cellp[b * HP + h]
                                     : (float)ctprev[(size_t)h * NT + (n - 1)];
        const float cn = sigm(cf) * ctold + sigm(ci) * tanhf(cg);
        ctnew[(size_t)h * NT + n] = (bf16)cn;
        hv[j] = (bf16)(sigm(co) * tanhf(cn));
      }
      *(bf16x4*)&Hsh[nloc][mh * 16 + quad * 4] = hv;
    }
    __syncthreads();
#pragma unroll
    for (int i2 = 0; i2 < 2; ++i2) {
      const int idx = i2 * 512 + tid;       // 128 rows x 8 chunks of 16B
      const int rrow = idx >> 3, off = idx & 7;
      *(u32x4*)&Hnew[(size_t)(n0 + rrow) * HP + bm * 64 + off * 8] =
          *(const u32x4*)&Hsh[rrow][off * 8];
    }
  }
}

// ---------------- output kernels (fp32 out) ----------------

__global__ void aux_kernel(const bf16* __restrict__ H, float* __restrict__ out, int s) {
  int idx = blockIdx.x * 256 + threadIdx.x;  // 8*256*100
  if (idx >= NT * 100) return;
  int n = idx / 100;
  int o = (idx % 100) * 4;
  int b = n >> 8, t = n & (T_ - 1);
  bf16x4 v = *(const bf16x4*)&H[(size_t)n * HP + 600 + o];
  f32x4 f = {(float)v[0], (float)v[1], (float)v[2], (float)v[3]};
  *(f32x4*)&out[AUX_OFF + ((size_t)((b * 2 + s) * T_ + t)) * 400 + o] = f;
}

__global__ void final_kernel(const bf16* __restrict__ H, const bf16* __restrict__ ct,
                             float* __restrict__ out) {
  int idx = blockIdx.x * 256 + threadIdx.x;
  if (idx < NT * 100) {
    int n = idx / 100;
    int o = (idx % 100) * 4;
    int b = n >> 8, t = n & (T_ - 1);
    bf16x4 v = *(const bf16x4*)&H[(size_t)n * HP + 600 + o];
    f32x4 f = {(float)v[0], (float)v[1], (float)v[2], (float)v[3]};
    *(f32x4*)&out[(size_t)n * 400 + o] = f;  // out_main [b][t][400]
    *(f32x4*)&out[AUX_OFF + ((size_t)((b * 2 + 1) * T_ + t)) * 400 + o] = f;
  } else {
    int j = idx - NT * 100;
    if (j < 8000) {
      int b = j / 1000, h = j % 1000;
      out[HT_OFF + j] = (float)H[(size_t)(b * T_ + 255) * HP + h];
    } else if (j < 16000) {
      int jj = j - 8000;
      int b = jj / 1000, h = jj % 1000;
      out[CT_OFF + jj] = (float)ct[(size_t)h * NT + b * T_ + 255];
    }
  }
}

// ---------------- launch ----------------

extern "C" void kernel_launch(void* const* d_in, const int* in_sizes, int n_in,
                              void* d_out, int out_size, void* d_ws, size_t ws_size,
                              hipStream_t stream) {
  const float* X    = (const float*)d_in[0];
  const float* hid  = (const float*)d_in[1];
  const float* cell = (const float*)d_in[2];
  const float* w1   = (const float*)d_in[3];
  const float* w2   = (const float*)d_in[4];
  const float* b2   = (const float*)d_in[5];
  float* out = (float*)d_out;

  char* ws = (char*)d_ws;
  size_t off = 0;
  auto alloc = [&](size_t bytes) {
    void* p = ws + off;
    off += (bytes + 255) & ~(size_t)255;
    return p;
  };
  bf16* W2q    = (bf16*)alloc((size_t)M_ * K2 * 2);     // 16 MB
  bf16* CbP    = (bf16*)alloc((size_t)NT * M_ * 2);     // 16 MB
  bf16* Hb0    = (bf16*)alloc((size_t)NT * HP * 2);     // 4 MB
  bf16* ctb0   = (bf16*)alloc((size_t)HP * NT * 2);     // 4 MB
  bf16* hidp   = (bf16*)alloc((size_t)B_ * HP * 2);
  float* cellp = (float*)alloc((size_t)B_ * HP * 4);
  // Union region: {W1q, XT} live only until the first GEMM; then {ctb1, Hb1}.
  char* R = (char*)alloc((size_t)12 * 1024 * 1024);     // 12 MB
  bf16* W1q  = (bf16*)R;                                // 8 MB
  bf16* XT   = (bf16*)(R + (size_t)8 * 1024 * 1024);    // 4 MB
  bf16* ctb1 = (bf16*)R;                                // 4 MB
  bf16* Hb1  = (bf16*)(R + (size_t)4 * 1024 * 1024);    // 4 MB

  bf16* Hb[2]  = {Hb0, Hb1};
  bf16* ctb[2] = {ctb0, ctb1};

  hipMemsetAsync(Hb[0], 0, (size_t)NT * HP * 2, stream);
  hipMemsetAsync(ctb[0], 0, (size_t)HP * NT * 2, stream);

  repack_w1<<<(M_ * K1) / 256, 256, 0, stream>>>(w1, W1q);
  repack_w2<<<(M_ * K2) / 256, 256, 0, stream>>>(w2, W2q);
  build_xt<<<(NT * K1) / 256, 256, 0, stream>>>(X, XT);
  build_hc<<<(B_ * HP) / 256, 256, 0, stream>>>(hid, cell, hidp, cellp);

  dim3 grid(16, 16);  // 256 blocks, 1/CU (144 KB LDS)
  gemm_step<false><<<grid, 512, 0, stream>>>(W1q, XT, nullptr, nullptr, CbP, b2,
                                             nullptr, nullptr, nullptr, nullptr, K1);
  for (int i = 0; i < 40; ++i) {
    int p = i & 1;
    gemm_step<true><<<grid, 512, 0, stream>>>(W2q, Hb[p], hidp, CbP, nullptr, nullptr,
                                              ctb[p], cellp, ctb[p ^ 1], Hb[p ^ 1], K2);
    if (i == 19) aux_kernel<<<800, 256, 0, stream>>>(Hb[p ^ 1], out, 0);
  }
  final_kernel<<<(NT * 100 + 16000 + 255) / 256, 256, 0, stream>>>(Hb[0], ctb[0], out);
}

// Round 5
// 1964.619 us; speedup vs baseline: 1.1914x; 1.0029x over previous
//
#include <hip/hip_runtime.h>
#include <hip/hip_bf16.h>
#include <math.h>

typedef __bf16 bf16;
typedef __bf16 bf16x8 __attribute__((ext_vector_type(8)));
typedef __bf16 bf16x4 __attribute__((ext_vector_type(4)));
typedef float f32x4 __attribute__((ext_vector_type(4)));
typedef unsigned int u32;
typedef u32 u32x4 __attribute__((ext_vector_type(4)));

#define NINP 400
#define HS   1000
#define HP   1024
#define B_   8
#define T_   256
#define NT   2048   /* B_*T_ */
#define K2   2048   /* 2*HP  */
#define K1   1024   /* 2*512 */
#define M_   4096   /* 4 gates * HP */

#define HT_OFF   819200
#define CT_OFF   827200
#define AUX_OFF  835200

typedef __attribute__((address_space(1))) const void gvoid;
typedef __attribute__((address_space(3))) void lvoid;

__device__ __forceinline__ void async_copy16(void* lds, const void* g) {
  __builtin_amdgcn_global_load_lds((gvoid*)g, (lvoid*)lds, 16, 0, 0);
}

__device__ __forceinline__ float sigm(float x) { return 1.0f / (1.0f + expf(-x)); }

// ---------------- repack kernels (fp32 inputs -> packed-m bf16) ----------------
// M-packing (unchanged): pm = (h>>5)*128 + ((h>>4)&1)*64 + g*16 + (h&15)
// Block bm (128 pm = 32 h) covers h in [bm*32, bm*32+32); wave mh's 4 m-tiles =
// gates 0..3 of h-subgroup.  C-layout (16x16): col=lane&15, row=quad*4+reg ->
// all 4 gates of a given h land in the same lane/reg across acc[0..3].

__global__ void repack_w1(const float* __restrict__ w1, bf16* __restrict__ W1q) {
  int idx = blockIdx.x * 256 + threadIdx.x;           // 4096*1024
  if (idx >= M_ * K1) return;
  int pm = idx >> 10, k = idx & 1023;
  int g = (pm >> 4) & 3;
  int h = (pm >> 7) * 32 + ((pm >> 6) & 1) * 16 + (pm & 15);
  float v = 0.0f;
  if (h < HS) {
    int c = g * HS + h;
    if (k < 512) { if (k < NINP) v = w1[(size_t)c * (NINP * 2) + k * 2 + 0]; }
    else { int j = k - 512; if (j < NINP) v = w1[(size_t)c * (NINP * 2) + j * 2 + 1]; }
  }
  W1q[idx] = (bf16)v;
}

__global__ void repack_w2(const float* __restrict__ w2, bf16* __restrict__ W2q) {
  int idx = blockIdx.x * 256 + threadIdx.x;           // 4096*2048
  if (idx >= M_ * K2) return;
  int pm = idx >> 11, k = idx & 2047;
  int g = (pm >> 4) & 3;
  int h = (pm >> 7) * 32 + ((pm >> 6) & 1) * 16 + (pm & 15);
  float v = 0.0f;
  if (h < HS) {
    int c = g * HS + h;
    if (k < HP) { if (k < HS) v = w2[(size_t)c * (HS * 2) + k * 2 + 0]; }
    else { int j = k - HP; if (j < HS) v = w2[(size_t)c * (HS * 2) + j * 2 + 1]; }
  }
  W2q[idx] = (bf16)v;
}

__global__ void build_xt(const float* __restrict__ X, bf16* __restrict__ XT) {
  int idx = blockIdx.x * 256 + threadIdx.x;           // 2048*1024
  if (idx >= NT * K1) return;
  int n = idx >> 10, k = idx & 1023;
  int b = n >> 8, t = n & (T_ - 1);
  float v = 0.0f;
  if (k < 512) { if (k < NINP && t > 0) v = X[((size_t)b * NINP + k) * T_ + t - 1]; }
  else { int j = k - 512; if (j < NINP) v = X[((size_t)b * NINP + j) * T_ + t]; }
  XT[idx] = (bf16)v;
}

__global__ void build_hc(const float* __restrict__ hid, const float* __restrict__ cell,
                         bf16* __restrict__ hidp, float* __restrict__ cellp) {
  int idx = blockIdx.x * 256 + threadIdx.x;           // 8*1024
  if (idx >= B_ * HP) return;
  int b = idx >> 10, k = idx & (HP - 1);
  hidp[idx]  = (k < HS) ? (bf16)hid[b * HS + k] : (bf16)0.0f;
  cellp[idx] = (k < HS) ? cell[b * HS + k] : 0.0f;
}

// ---------------- fused GEMM (+gating), 16x16x32 MFMA ----------------
// BM=128 x BN=128, BK=64, 4 waves (256 thr), wave = 64x64.  Grid 512 blocks =
// 2 blocks/CU (64 KB LDS each): per-workgroup barriers de-phase the two
// co-resident blocks, so one block's MFMA burst overlaps the other's LDS/stage
// burst (the r0 benefit r1-r4 lost at 1 block/CU).  Inside each block: r4's
// phase schedule -- per K-tile two phases
//   ph0: {ds_reads kc=0; bar; lgkm(0)+schedbar; setprio1 16xMFMA setprio0; bar}
//   ph1: {ds_reads kc=32; lgkm(0)+schedbar; bar (publishes: all reads of buf
//         done -> DMA may overwrite); stage tile t+2 -> THIS buf; vmcnt(8)
//         counted (never 0 in steady state); setprio1 16xMFMA setprio0; bar}
// 2 LDS buffers, tile j -> buf j&1, manual unroll-by-2 so buf is compile-time.
// vmcnt counting: 8 gload_lds per tile, tiles staged in order, in-order
// retirement => "stage(t+2) then vmcnt(8)" guarantees tile t+1 resident.
// All stage source pointers precomputed per-thread (VALU diet): A rows pa[4];
// gated-B lo-half (shifted H / hid at t==0) pb_lo[4], hi-half pb_hi[4];
// per-iter address math = ptr + it2*64.  Fragment reads keep the proven
// source-rotation conflict-free idiom.  CbIn (conv1) hoisted to registers.

template <bool GATED>
__global__ __launch_bounds__(256, 2) void gemm_step(
    const bf16* __restrict__ A,      // W2q [4096][2048] or W1q [4096][1024] packed-m
    const bf16* __restrict__ Bsrc,   // gated: Hprev [NT][HP]; plain: XT [NT][K1]
    const bf16* __restrict__ hidp,   // [B_][HP]
    const bf16* __restrict__ CbIn,   // gated: CbP [NT][4096] packed-m
    bf16* __restrict__ CbOut,        // plain: write CbP
    const float* __restrict__ b2,
    const bf16* __restrict__ ctprev, // [HP][NT]
    const float* __restrict__ cellp, // [B_][HP]
    bf16* __restrict__ ctnew,        // [HP][NT]
    bf16* __restrict__ Hnew,         // [NT][HP]
    int K) {
  __shared__ bf16 As[2][128][64];    // 32 KB
  __shared__ bf16 Bs[2][128][64];    // 32 KB

  const int tid = threadIdx.x;
  const int lane = tid & 63;
  const int w = tid >> 6;            // 0..3
  const int mh = w >> 1, nh = w & 1; // wave tile (mh*64, nh*64)
  const int dr = lane >> 3, c8 = lane & 7;
  const int swo = ((c8 - dr) & 7) * 8;     // staging source rotation
  const int quad = lane >> 4, col = lane & 15;

  // XCD swizzle over 512 blocks (r0-proven): xcd L&7 owns bm {4x..4x+3}
  // (2 MB W2q slice per XCD L2) x 16 n-blocks.
  const int L = blockIdx.y * gridDim.x + blockIdx.x;
  const int bm = (L & 7) * 4 + (L >> 7);           // 0..31 (128-pm blocks)
  const int n0 = ((L >> 3) & 15) * 128;

  // ---- gated: step-invariant conv1 contribution -> registers ----
  bf16x4 cb0[4], cb1[4], cb2[4], cb3[4];
  if (GATED) {
#pragma unroll
    for (int nt = 0; nt < 4; ++nt) {
      const int n = n0 + nh * 64 + nt * 16 + col;
      const size_t cb = (size_t)n * 4096 + (size_t)(bm * 128 + mh * 64) + quad * 4;
      cb0[nt] = *(const bf16x4*)&CbIn[cb + 0];
      cb1[nt] = *(const bf16x4*)&CbIn[cb + 16];
      cb2[nt] = *(const bf16x4*)&CbIn[cb + 32];
      cb3[nt] = *(const bf16x4*)&CbIn[cb + 48];
    }
  }

  // ---- precomputed stage source pointers (per thread) ----
  const bf16* pa[4];
  const bf16* pb_lo[4];
  const bf16* pb_hi[4];
#pragma unroll
  for (int j = 0; j < 4; ++j) {
    const int r = j * 32 + w * 8 + dr;             // 0..127
    pa[j] = A + (size_t)(bm * 128 + r) * K + swo;
    const int n = n0 + r;
    if (GATED) {
      const int t = n & (T_ - 1);
      pb_lo[j] = (t == 0) ? (hidp + (size_t)(n >> 8) * HP + swo)
                          : (Bsrc + (size_t)(n - 1) * HP + swo);
      pb_hi[j] = Bsrc + (size_t)n * HP + swo - HP; // + k0 (k0>=HP)
    } else {
      pb_lo[j] = Bsrc + (size_t)n * K + swo;
      pb_hi[j] = pb_lo[j];
    }
  }

  f32x4 acc[4][4];
#pragma unroll
  for (int i = 0; i < 4; ++i)
#pragma unroll
    for (int j = 0; j < 4; ++j) acc[i][j] = (f32x4){0.f, 0.f, 0.f, 0.f};

  auto stage = [&](int buf, int it2) {             // 8 x 16B gload_lds
#pragma unroll
    for (int j = 0; j < 4; ++j)
      async_copy16(&As[buf][j * 32 + w * 8][0], pa[j] + it2 * 64);
#pragma unroll
    for (int j = 0; j < 4; ++j) {
      const bf16* src = (GATED && it2 >= 16) ? pb_hi[j] : pb_lo[j];
      async_copy16(&Bs[buf][j * 32 + w * 8][0], src + it2 * 64);
    }
  };

  const int NIT = K >> 6;            // 16 or 32 (even)

  auto kstep = [&](int it2, int buf) {
    // ---------- phase 0 (kc = 0) ----------
    {
      bf16x8 av[4], bv[4];
#pragma unroll
      for (int mt = 0; mt < 4; ++mt) {
        const int rA = mh * 64 + mt * 16 + col;
        av[mt] = *(const bf16x8*)&As[buf][rA][((quad + rA) & 7) * 8];
      }
#pragma unroll
      for (int nt = 0; nt < 4; ++nt) {
        const int rB = nh * 64 + nt * 16 + col;
        bv[nt] = *(const bf16x8*)&Bs[buf][rB][((quad + rB) & 7) * 8];
      }
      __builtin_amdgcn_s_barrier();
      asm volatile("s_waitcnt lgkmcnt(0)" ::: "memory");
      __builtin_amdgcn_sched_barrier(0);
      __builtin_amdgcn_s_setprio(1);
#pragma unroll
      for (int mt = 0; mt < 4; ++mt)
#pragma unroll
        for (int nt = 0; nt < 4; ++nt)
          acc[mt][nt] = __builtin_amdgcn_mfma_f32_16x16x32_bf16(av[mt], bv[nt], acc[mt][nt], 0, 0, 0);
      __builtin_amdgcn_s_setprio(0);
      __builtin_amdgcn_s_barrier();
    }
    // ---------- phase 1 (kc = 32) ----------
    {
      bf16x8 av[4], bv[4];
#pragma unroll
      for (int mt = 0; mt < 4; ++mt) {
        const int rA = mh * 64 + mt * 16 + col;
        av[mt] = *(const bf16x8*)&As[buf][rA][((4 + quad + rA) & 7) * 8];
      }
#pragma unroll
      for (int nt = 0; nt < 4; ++nt) {
        const int rB = nh * 64 + nt * 16 + col;
        bv[nt] = *(const bf16x8*)&Bs[buf][rB][((4 + quad + rB) & 7) * 8];
      }
      asm volatile("s_waitcnt lgkmcnt(0)" ::: "memory");  // my reads in regs
      __builtin_amdgcn_sched_barrier(0);
      __builtin_amdgcn_s_barrier();                       // ALL reads of buf done
      if (it2 + 2 < NIT) {
        stage(buf, it2 + 2);                              // overwrite this buf
        asm volatile("s_waitcnt vmcnt(8)" ::: "memory");  // tile t+1 resident
      } else {
        asm volatile("s_waitcnt vmcnt(0)" ::: "memory");
      }
      __builtin_amdgcn_sched_barrier(0);
      __builtin_amdgcn_s_setprio(1);
#pragma unroll
      for (int mt = 0; mt < 4; ++mt)
#pragma unroll
        for (int nt = 0; nt < 4; ++nt)
          acc[mt][nt] = __builtin_amdgcn_mfma_f32_16x16x32_bf16(av[mt], bv[nt], acc[mt][nt], 0, 0, 0);
      __builtin_amdgcn_s_setprio(0);
      __builtin_amdgcn_s_barrier();
    }
  };

  stage(0, 0);
  stage(1, 1);
  asm volatile("s_waitcnt vmcnt(8)" ::: "memory");  // CbIn + tile0 retired
  __builtin_amdgcn_s_barrier();

  for (int it2 = 0; it2 < NIT; it2 += 2) {
    kstep(it2, 0);
    kstep(it2 + 1, 1);
  }
  __syncthreads();                   // drain for epilogue overlay

  if (!GATED) {
    // epilogue: pack C block [128 n][128 pm] via LDS overlay on As (32 KB)
    bf16 (*Csh)[128] = (bf16(*)[128])&As[0][0][0];
#pragma unroll
    for (int mt = 0; mt < 4; ++mt) {        // mt = gate
#pragma unroll
      for (int nt = 0; nt < 4; ++nt) {
        const int nloc = nh * 64 + nt * 16 + col;
        bf16x4 v;
#pragma unroll
        for (int j = 0; j < 4; ++j) {
          const int h = bm * 32 + mh * 16 + quad * 4 + j;
          const float bias = (h < HS) ? b2[mt * HS + h] : 0.0f;
          v[j] = (bf16)(acc[mt][nt][j] + bias);
        }
        *(bf16x4*)&Csh[nloc][mh * 64 + mt * 16 + quad * 4] = v;
      }
    }
    __syncthreads();
#pragma unroll
    for (int i2 = 0; i2 < 8; ++i2) {
      const int idx = i2 * 256 + tid;       // 128 rows x 16 chunks of 16B
      const int rrow = idx >> 4, off = idx & 15;
      *(u32x4*)&CbOut[(size_t)(n0 + rrow) * 4096 + bm * 128 + off * 8] =
          *(const u32x4*)&Csh[rrow][off * 8];
    }
  } else {
    bf16 (*Hsh)[32] = (bf16(*)[32])&As[0][0][0];   // [128 n][32 h] = 8 KB
#pragma unroll
    for (int nt = 0; nt < 4; ++nt) {
      const int nloc = nh * 64 + nt * 16 + col;
      const int n = n0 + nloc;
      const int b = n >> 8;
      const int t = n & (T_ - 1);
      bf16x4 hv;
#pragma unroll
      for (int j = 0; j < 4; ++j) {
        const int h = bm * 32 + mh * 16 + quad * 4 + j;
        const float ci = acc[0][nt][j] + (float)cb0[nt][j];
        const float co = acc[1][nt][j] + (float)cb1[nt][j];
        const float cg = acc[2][nt][j] + (float)cb2[nt][j];
        const float cf = acc[3][nt][j] + (float)cb3[nt][j];
        const float ctold = (t == 0) ? cellp[b * HP + h]
                                     : (float)ctprev[(size_t)h * NT + (n - 1)];
        const float cn = sigm(cf) * ctold + sigm(ci) * tanhf(cg);
        ctnew[(size_t)h * NT + n] = (bf16)cn;
        hv[j] = (bf16)(sigm(co) * tanhf(cn));
      }
      *(bf16x4*)&Hsh[nloc][mh * 16 + quad * 4] = hv;
    }
    __syncthreads();
#pragma unroll
    for (int i2 = 0; i2 < 2; ++i2) {
      const int idx = i2 * 256 + tid;       // 128 rows x 4 chunks of 16B
      const int rrow = idx >> 2, off = idx & 3;
      *(u32x4*)&Hnew[(size_t)(n0 + rrow) * HP + bm * 32 + off * 8] =
          *(const u32x4*)&Hsh[rrow][off * 8];
    }
  }
}

// ---------------- output kernels (fp32 out) ----------------

__global__ void aux_kernel(const bf16* __restrict__ H, float* __restrict__ out, int s) {
  int idx = blockIdx.x * 256 + threadIdx.x;  // 8*256*100
  if (idx >= NT * 100) return;
  int n = idx / 100;
  int o = (idx % 100) * 4;
  int b = n >> 8, t = n & (T_ - 1);
  bf16x4 v = *(const bf16x4*)&H[(size_t)n * HP + 600 + o];
  f32x4 f = {(float)v[0], (float)v[1], (float)v[2], (float)v[3]};
  *(f32x4*)&out[AUX_OFF + ((size_t)((b * 2 + s) * T_ + t)) * 400 + o] = f;
}

__global__ void final_kernel(const bf16* __restrict__ H, const bf16* __restrict__ ct,
                             float* __restrict__ out) {
  int idx = blockIdx.x * 256 + threadIdx.x;
  if (idx < NT * 100) {
    int n = idx / 100;
    int o = (idx % 100) * 4;
    int b = n >> 8, t = n & (T_ - 1);
    bf16x4 v = *(const bf16x4*)&H[(size_t)n * HP + 600 + o];
    f32x4 f = {(float)v[0], (float)v[1], (float)v[2], (float)v[3]};
    *(f32x4*)&out[(size_t)n * 400 + o] = f;  // out_main [b][t][400]
    *(f32x4*)&out[AUX_OFF + ((size_t)((b * 2 + 1) * T_ + t)) * 400 + o] = f;
  } else {
    int j = idx - NT * 100;
    if (j < 8000) {
      int b = j / 1000, h = j % 1000;
      out[HT_OFF + j] = (float)H[(size_t)(b * T_ + 255) * HP + h];
    } else if (j < 16000) {
      int jj = j - 8000;
      int b = jj / 1000, h = jj % 1000;
      out[CT_OFF + jj] = (float)ct[(size_t)h * NT + b * T_ + 255];
    }
  }
}

// ---------------- launch ----------------

extern "C" void kernel_launch(void* const* d_in, const int* in_sizes, int n_in,
                              void* d_out, int out_size, void* d_ws, size_t ws_size,
                              hipStream_t stream) {
  const float* X    = (const float*)d_in[0];
  const float* hid  = (const float*)d_in[1];
  const float* cell = (const float*)d_in[2];
  const float* w1   = (const float*)d_in[3];
  const float* w2   = (const float*)d_in[4];
  const float* b2   = (const float*)d_in[5];
  float* out = (float*)d_out;

  char* ws = (char*)d_ws;
  size_t off = 0;
  auto alloc = [&](size_t bytes) {
    void* p = ws + off;
    off += (bytes + 255) & ~(size_t)255;
    return p;
  };
  bf16* W2q    = (bf16*)alloc((size_t)M_ * K2 * 2);     // 16 MB
  bf16* CbP    = (bf16*)alloc((size_t)NT * M_ * 2);     // 16 MB
  bf16* Hb0    = (bf16*)alloc((size_t)NT * HP * 2);     // 4 MB
  bf16* ctb0   = (bf16*)alloc((size_t)HP * NT * 2);     // 4 MB
  bf16* hidp   = (bf16*)alloc((size_t)B_ * HP * 2);
  float* cellp = (float*)alloc((size_t)B_ * HP * 4);
  // Union region: {W1q, XT} live only until the first GEMM; then {ctb1, Hb1}.
  char* R = (char*)alloc((size_t)12 * 1024 * 1024);     // 12 MB
  bf16* W1q  = (bf16*)R;                                // 8 MB
  bf16* XT   = (bf16*)(R + (size_t)8 * 1024 * 1024);    // 4 MB
  bf16* ctb1 = (bf16*)R;                                // 4 MB
  bf16* Hb1  = (bf16*)(R + (size_t)4 * 1024 * 1024);    // 4 MB

  bf16* Hb[2]  = {Hb0, Hb1};
  bf16* ctb[2] = {ctb0, ctb1};

  hipMemsetAsync(Hb[0], 0, (size_t)NT * HP * 2, stream);
  hipMemsetAsync(ctb[0], 0, (size_t)HP * NT * 2, stream);

  repack_w1<<<(M_ * K1) / 256, 256, 0, stream>>>(w1, W1q);
  repack_w2<<<(M_ * K2) / 256, 256, 0, stream>>>(w2, W2q);
  build_xt<<<(NT * K1) / 256, 256, 0, stream>>>(X, XT);
  build_hc<<<(B_ * HP) / 256, 256, 0, stream>>>(hid, cell, hidp, cellp);

  dim3 grid(NT / 128, M_ / 128);  // 16 x 32 = 512 blocks, 2/CU (64 KB LDS)
  gemm_step<false><<<grid, 256, 0, stream>>>(W1q, XT, nullptr, nullptr, CbP, b2,
                                             nullptr, nullptr, nullptr, nullptr, K1);
  for (int i = 0; i < 40; ++i) {
    int p = i & 1;
    gemm_step<true><<<grid, 256, 0, stream>>>(W2q, Hb[p], hidp, CbP, nullptr, nullptr,
                                              ctb[p], cellp, ctb[p ^ 1], Hb[p ^ 1], K2);
    if (i == 19) aux_kernel<<<800, 256, 0, stream>>>(Hb[p ^ 1], out, 0);
  }
  final_kernel<<<(NT * 100 + 16000 + 255) / 256, 256, 0, stream>>>(Hb[0], ctb[0], out);
}

// Round 7
// 1957.444 us; speedup vs baseline: 1.1958x; 1.0037x over previous
//
#include <hip/hip_runtime.h>
#include <hip/hip_bf16.h>
#include <math.h>

typedef __bf16 bf16;
typedef __bf16 bf16x8 __attribute__((ext_vector_type(8)));
typedef __bf16 bf16x4 __attribute__((ext_vector_type(4)));
typedef float f32x4 __attribute__((ext_vector_type(4)));
typedef unsigned int u32;
typedef u32 u32x4 __attribute__((ext_vector_type(4)));

#define NINP 400
#define HS   1000
#define HP   1024
#define B_   8
#define T_   256
#define NT   2048   /* B_*T_ */
#define M_   4096   /* 4 gates * HP */

#define HT_OFF   819200
#define CT_OFF   827200
#define AUX_OFF  835200

typedef __attribute__((address_space(1))) const void gvoid;
typedef __attribute__((address_space(3))) void lvoid;

__device__ __forceinline__ void async_copy16(void* lds, const void* g) {
  __builtin_amdgcn_global_load_lds((gvoid*)g, (lvoid*)lds, 16, 0, 0);
}

__device__ __forceinline__ float sigm(float x) { return 1.0f / (1.0f + expf(-x)); }

// ---------------- repack kernels (fp32 inputs -> packed-m bf16) ----------------
// M-packing (unchanged): pm = (h>>5)*128 + ((h>>4)&1)*16... see prior rounds.
// W layout: k < KH -> tap0 (applied to shifted input), k >= KH -> tap1.

__global__ void repack_w1(const float* __restrict__ w1, bf16* __restrict__ W1q) {
  int idx = blockIdx.x * 256 + threadIdx.x;           // 4096*1024
  if (idx >= M_ * 1024) return;
  int pm = idx >> 10, k = idx & 1023;
  int g = (pm >> 4) & 3;
  int h = (pm >> 7) * 32 + ((pm >> 6) & 1) * 16 + (pm & 15);
  float v = 0.0f;
  if (h < HS) {
    int c = g * HS + h;
    if (k < 512) { if (k < NINP) v = w1[(size_t)c * (NINP * 2) + k * 2 + 0]; }
    else { int j = k - 512; if (j < NINP) v = w1[(size_t)c * (NINP * 2) + j * 2 + 1]; }
  }
  W1q[idx] = (bf16)v;
}

__global__ void repack_w2(const float* __restrict__ w2, bf16* __restrict__ W2q) {
  int idx = blockIdx.x * 256 + threadIdx.x;           // 4096*2048
  if (idx >= M_ * 2048) return;
  int pm = idx >> 11, k = idx & 2047;
  int g = (pm >> 4) & 3;
  int h = (pm >> 7) * 32 + ((pm >> 6) & 1) * 16 + (pm & 15);
  float v = 0.0f;
  if (h < HS) {
    int c = g * HS + h;
    if (k < HP) { if (k < HS) v = w2[(size_t)c * (HS * 2) + k * 2 + 0]; }
    else { int j = k - HP; if (j < HS) v = w2[(size_t)c * (HS * 2) + j * 2 + 1]; }
  }
  W2q[idx] = (bf16)v;
}

// XS[n][k] (k<512): tap1 source X[b][k][t]; tap0 read = row n-1 (shift at read).
__global__ void build_xs(const float* __restrict__ X, bf16* __restrict__ XS) {
  int idx = blockIdx.x * 256 + threadIdx.x;           // 2048*512
  if (idx >= NT * 512) return;
  int n = idx >> 9, k = idx & 511;
  int b = n >> 8, t = n & (T_ - 1);
  float v = 0.0f;
  if (k < NINP) v = X[((size_t)b * NINP + k) * T_ + t];
  XS[idx] = (bf16)v;
}

__global__ void build_hc(const float* __restrict__ hid, const float* __restrict__ cell,
                         bf16* __restrict__ hidp, float* __restrict__ cellp) {
  int idx = blockIdx.x * 256 + threadIdx.x;           // 8*1024
  if (idx >= B_ * HP) return;
  int b = idx >> 10, k = idx & (HP - 1);
  hidp[idx]  = (k < HS) ? (bf16)hid[b * HS + k] : (bf16)0.0f;
  cellp[idx] = (k < HS) ? cell[b * HS + k] : 0.0f;
}

// ---------------- fused GEMM (+gating), 16x16x32 MFMA, tap-shared staging ----------------
// BM=128 x BN=128, 4 waves (64x64 each), 2 blocks/CU, r5's phase schedule.
// K viewed as KH x {tap0,tap1}.  Per k-slice pair j (BK=32 per tap): stage
// {A-lo (W tap0 cols), A-hi (W tap1 cols), Hs = B[n0..n0+127] slice j}.  Hs
// staged ONCE serves BOTH taps: hi reads Hs[rB], lo reads Hs[rB-1]; boundary
// row B[n0-1] (hid/zeros at t==0, only possible at rB==0) lives in H0row.
// LDS writes -25%, stage instrs 8->6/thread/K64, B-side L2 traffic halved.
// 32-col tiles use paired-row swizzle: logical (r,k8) -> phys elem
// (r>>1)*64 + ((k8 + 4*(r&1) + ((r>>1)&7))&7)*8; DMA source pre-permuted via
// the inverse map.  r7 FIX: lo-tap fragment base computed PER nt from its own
// row (r6 reused the nt=0 base, garbage for the nh==0,col==0 lane at nt>=1).
// Schedule per pair: ph-lo {reads; BAR; lgkm0+SB; setprio 16xMFMA; BAR},
// ph-hi {reads; lgkm0+SB; BAR(all reads of buf done); stage(j+2); vmcnt(6);
// SB; setprio 16xMFMA; BAR}.  vmcnt never 0 in steady state.

template <bool GATED>
__global__ __launch_bounds__(256, 2) void gemm_step(
    const bf16* __restrict__ A,      // W2q [4096][2048] or W1q [4096][1024] packed-m
    const bf16* __restrict__ Bsrc,   // gated: Hprev [NT][1024]; plain: XS [NT][512]
    const bf16* __restrict__ hidp,   // [B_][HP]
    const bf16* __restrict__ CbIn,   // gated: CbP [NT][4096] packed-m
    bf16* __restrict__ CbOut,        // plain: write CbP
    const float* __restrict__ b2,
    const bf16* __restrict__ ctprev, // [HP][NT]
    const float* __restrict__ cellp, // [B_][HP]
    bf16* __restrict__ ctnew,        // [HP][NT]
    bf16* __restrict__ Hnew,         // [NT][HP]
    int KH, int BS) {                // KH = K/2 (1024 or 512); BS = B row stride
  __shared__ bf16 SM[2][3][4096];    // [buf][Alo,Ahi,Hs][128x32 swizzled] = 48 KB
  __shared__ __align__(16) bf16 H0row[1024];  // B[n0-1] row slice (KH elems used)

  const int tid = threadIdx.x;
  const int lane = tid & 63;
  const int w = tid >> 6;            // 0..3
  const int mh = w >> 1, nh = w & 1; // wave tile (mh*64, nh*64)
  const int quad = lane >> 4, col = lane & 15;
  const int K = KH * 2;

  // XCD swizzle over 512 blocks (r0-proven)
  const int L = blockIdx.y * gridDim.x + blockIdx.x;
  const int bm = (L & 7) * 4 + (L >> 7);           // 0..31 (128-pm blocks)
  const int n0 = ((L >> 3) & 15) * 128;

  // ---- gated: step-invariant conv1 contribution -> registers ----
  bf16x4 cb0[4], cb1[4], cb2[4], cb3[4];
  if (GATED) {
#pragma unroll
    for (int nt = 0; nt < 4; ++nt) {
      const int n = n0 + nh * 64 + nt * 16 + col;
      const size_t cb = (size_t)n * 4096 + (size_t)(bm * 128 + mh * 64) + quad * 4;
      cb0[nt] = *(const bf16x4*)&CbIn[cb + 0];
      cb1[nt] = *(const bf16x4*)&CbIn[cb + 16];
      cb2[nt] = *(const bf16x4*)&CbIn[cb + 32];
      cb3[nt] = *(const bf16x4*)&CbIn[cb + 48];
    }
  }

  // ---- per-lane fragment-read constants (swizzled layout) ----
  const int colh = col >> 1;
  const int slotA = ((quad + 4 * (col & 1) + (colh & 7)) & 7) * 8;   // elems
  const int baseA   = (mh * 32 + colh) * 64 + slotA;                 // A-lo/A-hi
  const int baseBhi = (nh * 32 + colh) * 64 + slotA;                 // Hs[rB]
  // lo-tap bases, PER nt (r7 fix): row r = nh*64 + nt*16 + col - 1
  const bool useH0 = (nh == 0 && col == 0);        // only nt==0 hits n0-1
  int baseLo[4];
#pragma unroll
  for (int nt = 0; nt < 4; ++nt) {
    const int r = nh * 64 + nt * 16 + col - 1;     // -1 only for useH0,nt=0
    const int pr = r >> 1;                         // arithmetic shift
    baseLo[nt] = pr * 64 + (((quad + 4 * (r & 1) + (pr & 7)) & 7) * 8);
  }

  // ---- per-thread DMA source pointers via inverse swizzle ----
  const bf16* paLo[2];
  const bf16* pbs[2];
#pragma unroll
  for (int l = 0; l < 2; ++l) {
    const int f = l * 256 + tid;
    const int pr = f >> 3, sl = f & 7;
    const int u = (sl - (pr & 7)) & 7;
    const int r = 2 * pr + (u >> 2), k8 = u & 3;
    paLo[l] = A + (size_t)(bm * 128 + r) * K + k8 * 8;
    pbs[l]  = Bsrc + (size_t)(n0 + r) * BS + k8 * 8;
  }

  f32x4 acc[4][4];
#pragma unroll
  for (int i = 0; i < 4; ++i)
#pragma unroll
    for (int j = 0; j < 4; ++j) acc[i][j] = (f32x4){0.f, 0.f, 0.f, 0.f};

  auto stage = [&](int buf, int p2) {              // 6 x 16B gload_lds
#pragma unroll
    for (int l = 0; l < 2; ++l) {
      async_copy16(&SM[buf][0][(l * 256 + w * 64) * 8], paLo[l] + p2 * 32);
      async_copy16(&SM[buf][1][(l * 256 + w * 64) * 8], paLo[l] + KH + p2 * 32);
      async_copy16(&SM[buf][2][(l * 256 + w * 64) * 8], pbs[l] + p2 * 32);
    }
  };

  const int NP = KH >> 5;            // 32 (gated) or 16 (plain), even

  auto kpair = [&](int p2, int buf) {
    // ---------- phase LO (tap0: W-lo x B[n-1]) ----------
    {
      bf16x8 av[4], bv[4];
#pragma unroll
      for (int mt = 0; mt < 4; ++mt)
        av[mt] = *(const bf16x8*)&SM[buf][0][baseA + mt * 512];
      {
        const bf16* p0 = useH0 ? &H0row[p2 * 32 + quad * 8]
                               : &SM[buf][2][baseLo[0]];
        bv[0] = *(const bf16x8*)p0;
      }
#pragma unroll
      for (int nt = 1; nt < 4; ++nt)
        bv[nt] = *(const bf16x8*)&SM[buf][2][baseLo[nt]];
      __builtin_amdgcn_s_barrier();
      asm volatile("s_waitcnt lgkmcnt(0)" ::: "memory");
      __builtin_amdgcn_sched_barrier(0);
      __builtin_amdgcn_s_setprio(1);
#pragma unroll
      for (int mt = 0; mt < 4; ++mt)
#pragma unroll
        for (int nt = 0; nt < 4; ++nt)
          acc[mt][nt] = __builtin_amdgcn_mfma_f32_16x16x32_bf16(av[mt], bv[nt], acc[mt][nt], 0, 0, 0);
      __builtin_amdgcn_s_setprio(0);
      __builtin_amdgcn_s_barrier();
    }
    // ---------- phase HI (tap1: W-hi x B[n]) ----------
    {
      bf16x8 av[4], bv[4];
#pragma unroll
      for (int mt = 0; mt < 4; ++mt)
        av[mt] = *(const bf16x8*)&SM[buf][1][baseA + mt * 512];
#pragma unroll
      for (int nt = 0; nt < 4; ++nt)
        bv[nt] = *(const bf16x8*)&SM[buf][2][baseBhi + nt * 512];
      asm volatile("s_waitcnt lgkmcnt(0)" ::: "memory");
      __builtin_amdgcn_sched_barrier(0);
      __builtin_amdgcn_s_barrier();                // ALL reads of buf done
      if (p2 + 2 < NP) {
        stage(buf, p2 + 2);                        // overwrite this buf
        asm volatile("s_waitcnt vmcnt(6)" ::: "memory");  // pair p2+1 resident
      } else {
        asm volatile("s_waitcnt vmcnt(0)" ::: "memory");
      }
      __builtin_amdgcn_sched_barrier(0);
      __builtin_amdgcn_s_setprio(1);
#pragma unroll
      for (int mt = 0; mt < 4; ++mt)
#pragma unroll
        for (int nt = 0; nt < 4; ++nt)
          acc[mt][nt] = __builtin_amdgcn_mfma_f32_16x16x32_bf16(av[mt], bv[nt], acc[mt][nt], 0, 0, 0);
      __builtin_amdgcn_s_setprio(0);
      __builtin_amdgcn_s_barrier();
    }
  };

  // ---- prologue: H0row + first two pairs ----
  if (GATED) {
    if (w < 2) {
      const bf16* s = ((n0 & 255) == 0)
          ? (hidp + (size_t)(n0 >> 8) * HP + lane * 8 + w * 512)
          : (Bsrc + (size_t)(n0 - 1) * BS + lane * 8 + w * 512);
      async_copy16(&H0row[w * 512], s);
    }
  } else {
    if ((n0 & 255) == 0) {
      if (tid < 64) *(u32x4*)&H0row[tid * 8] = (u32x4){0, 0, 0, 0};
    } else if (w < 1) {
      async_copy16(&H0row[w * 512], Bsrc + (size_t)(n0 - 1) * BS + lane * 8 + w * 512);
    }
  }
  stage(0, 0);
  stage(1, 1);
  __syncthreads();                   // drain everything; pairs 0,1 + H0row ready

  for (int p = 0; p < NP; p += 2) {
    kpair(p, 0);
    kpair(p + 1, 1);
  }
  __syncthreads();                   // drain for epilogue overlay

  if (!GATED) {
    // epilogue: pack C block [128 n][128 pm] via LDS overlay (32 KB of SM)
    bf16 (*Csh)[128] = (bf16(*)[128])&SM[0][0][0];
#pragma unroll
    for (int mt = 0; mt < 4; ++mt) {        // mt = gate
#pragma unroll
      for (int nt = 0; nt < 4; ++nt) {
        const int nloc = nh * 64 + nt * 16 + col;
        bf16x4 v;
#pragma unroll
        for (int j = 0; j < 4; ++j) {
          const int h = bm * 32 + mh * 16 + quad * 4 + j;
          const float bias = (h < HS) ? b2[mt * HS + h] : 0.0f;
          v[j] = (bf16)(acc[mt][nt][j] + bias);
        }
        *(bf16x4*)&Csh[nloc][mh * 64 + mt * 16 + quad * 4] = v;
      }
    }
    __syncthreads();
#pragma unroll
    for (int i2 = 0; i2 < 8; ++i2) {
      const int idx = i2 * 256 + tid;       // 128 rows x 16 chunks of 16B
      const int rrow = idx >> 4, off = idx & 15;
      *(u32x4*)&CbOut[(size_t)(n0 + rrow) * 4096 + bm * 128 + off * 8] =
          *(const u32x4*)&Csh[rrow][off * 8];
    }
  } else {
    bf16 (*Hsh)[32] = (bf16(*)[32])&SM[0][0][0];   // [128 n][32 h] = 8 KB
#pragma unroll
    for (int nt = 0; nt < 4; ++nt) {
      const int nloc = nh * 64 + nt * 16 + col;
      const int n = n0 + nloc;
      const int b = n >> 8;
      const int t = n & (T_ - 1);
      bf16x4 hv;
#pragma unroll
      for (int j = 0; j < 4; ++j) {
        const int h = bm * 32 + mh * 16 + quad * 4 + j;
        const float ci = acc[0][nt][j] + (float)cb0[nt][j];
        const float co = acc[1][nt][j] + (float)cb1[nt][j];
        const float cg = acc[2][nt][j] + (float)cb2[nt][j];
        const float cf = acc[3][nt][j] + (float)cb3[nt][j];
        const float ctold = (t == 0) ? cellp[b * HP + h]
                                     : (float)ctprev[(size_t)h * NT + (n - 1)];
        const float cn = sigm(cf) * ctold + sigm(ci) * tanhf(cg);
        ctnew[(size_t)h * NT + n] = (bf16)cn;
        hv[j] = (bf16)(sigm(co) * tanhf(cn));
      }
      *(bf16x4*)&Hsh[nloc][mh * 16 + quad * 4] = hv;
    }
    __syncthreads();
#pragma unroll
    for (int i2 = 0; i2 < 2; ++i2) {
      const int idx = i2 * 256 + tid;       // 128 rows x 4 chunks of 16B
      const int rrow = idx >> 2, off = idx & 3;
      *(u32x4*)&Hnew[(size_t)(n0 + rrow) * HP + bm * 32 + off * 8] =
          *(const u32x4*)&Hsh[rrow][off * 8];
    }
  }
}

// ---------------- output kernels (fp32 out) ----------------

__global__ void aux_kernel(const bf16* __restrict__ H, float* __restrict__ out, int s) {
  int idx = blockIdx.x * 256 + threadIdx.x;  // 8*256*100
  if (idx >= NT * 100) return;
  int n = idx / 100;
  int o = (idx % 100) * 4;
  int b = n >> 8, t = n & (T_ - 1);
  bf16x4 v = *(const bf16x4*)&H[(size_t)n * HP + 600 + o];
  f32x4 f = {(float)v[0], (float)v[1], (float)v[2], (float)v[3]};
  *(f32x4*)&out[AUX_OFF + ((size_t)((b * 2 + s) * T_ + t)) * 400 + o] = f;
}

__global__ void final_kernel(const bf16* __restrict__ H, const bf16* __restrict__ ct,
                             float* __restrict__ out) {
  int idx = blockIdx.x * 256 + threadIdx.x;
  if (idx < NT * 100) {
    int n = idx / 100;
    int o = (idx % 100) * 4;
    int b = n >> 8, t = n & (T_ - 1);
    bf16x4 v = *(const bf16x4*)&H[(size_t)n * HP + 600 + o];
    f32x4 f = {(float)v[0], (float)v[1], (float)v[2], (float)v[3]};
    *(f32x4*)&out[(size_t)n * 400 + o] = f;  // out_main [b][t][400]
    *(f32x4*)&out[AUX_OFF + ((size_t)((b * 2 + 1) * T_ + t)) * 400 + o] = f;
  } else {
    int j = idx - NT * 100;
    if (j < 8000) {
      int b = j / 1000, h = j % 1000;
      out[HT_OFF + j] = (float)H[(size_t)(b * T_ + 255) * HP + h];
    } else if (j < 16000) {
      int jj = j - 8000;
      int b = jj / 1000, h = jj % 1000;
      out[CT_OFF + jj] = (float)ct[(size_t)h * NT + b * T_ + 255];
    }
  }
}

// ---------------- launch ----------------

extern "C" void kernel_launch(void* const* d_in, const int* in_sizes, int n_in,
                              void* d_out, int out_size, void* d_ws, size_t ws_size,
                              hipStream_t stream) {
  const float* X    = (const float*)d_in[0];
  const float* hid  = (const float*)d_in[1];
  const float* cell = (const float*)d_in[2];
  const float* w1   = (const float*)d_in[3];
  const float* w2   = (const float*)d_in[4];
  const float* b2   = (const float*)d_in[5];
  float* out = (float*)d_out;

  char* ws = (char*)d_ws;
  size_t off = 0;
  auto alloc = [&](size_t bytes) {
    void* p = ws + off;
    off += (bytes + 255) & ~(size_t)255;
    return p;
  };
  bf16* W2q    = (bf16*)alloc((size_t)M_ * 2048 * 2);   // 16 MB
  bf16* CbP    = (bf16*)alloc((size_t)NT * M_ * 2);     // 16 MB
  bf16* Hb0    = (bf16*)alloc((size_t)NT * HP * 2);     // 4 MB
  bf16* ctb0   = (bf16*)alloc((size_t)HP * NT * 2);     // 4 MB
  bf16* hidp   = (bf16*)alloc((size_t)B_ * HP * 2);
  float* cellp = (float*)alloc((size_t)B_ * HP * 4);
  // Union region: {W1q, XS} live only until the first GEMM; then {ctb1, Hb1}.
  char* R = (char*)alloc((size_t)12 * 1024 * 1024);     // 12 MB
  bf16* W1q  = (bf16*)R;                                // 8 MB
  bf16* XS   = (bf16*)(R + (size_t)8 * 1024 * 1024);    // 2 MB
  bf16* ctb1 = (bf16*)R;                                // 4 MB
  bf16* Hb1  = (bf16*)(R + (size_t)4 * 1024 * 1024);    // 4 MB

  bf16* Hb[2]  = {Hb0, Hb1};
  bf16* ctb[2] = {ctb0, ctb1};

  hipMemsetAsync(Hb[0], 0, (size_t)NT * HP * 2, stream);
  hipMemsetAsync(ctb[0], 0, (size_t)HP * NT * 2, stream);

  repack_w1<<<(M_ * 1024) / 256, 256, 0, stream>>>(w1, W1q);
  repack_w2<<<(M_ * 2048) / 256, 256, 0, stream>>>(w2, W2q);
  build_xs<<<(NT * 512) / 256, 256, 0, stream>>>(X, XS);
  build_hc<<<(B_ * HP) / 256, 256, 0, stream>>>(hid, cell, hidp, cellp);

  dim3 grid(NT / 128, M_ / 128);  // 16 x 32 = 512 blocks, 2/CU (50 KB LDS)
  gemm_step<false><<<grid, 256, 0, stream>>>(W1q, XS, nullptr, nullptr, CbP, b2,
                                             nullptr, nullptr, nullptr, nullptr,
                                             512, 512);
  for (int i = 0; i < 40; ++i) {
    int p = i & 1;
    gemm_step<true><<<grid, 256, 0, stream>>>(W2q, Hb[p], hidp, CbP, nullptr, nullptr,
                                              ctb[p], cellp, ctb[p ^ 1], Hb[p ^ 1],
                                              1024, 1024);
    if (i == 19) aux_kernel<<<800, 256, 0, stream>>>(Hb[p ^ 1], out, 0);
  }
  final_kernel<<<(NT * 100 + 16000 + 255) / 256, 256, 0, stream>>>(Hb[0], ctb[0], out);
}